// Round 2
// baseline (352.458 us; speedup 1.0000x reference)
//
#include <hip/hip_runtime.h>
#include <hip/hip_cooperative_groups.h>
#include <stdint.h>

namespace cg = cooperative_groups;

// Problem constants (from reference): D1=3, S=384, B=32, N=65536
#define NPTS 65536
#define NB   32
#define SS   384

// RN(1/3) in f32 = 0x3EAAAAAB
#define C3INV 0.333333343267440796f

// Fixed-point scale for histogram accumulation (R16): int LDS atomics emit a
// single native ds_add_u32. |bin sum| < ~65k -> scale 2^15 fits int32 with
// margin; quantization ~1.5e-5/add, worst bin ~6e-3 << 0.5 threshold.
#define FP_SCALE 32768.0f
#define FP_INV   (1.0f / 32768.0f)

// ---- LOCKED NUMERICS (R7, passed absmax<=0.0156) ----
__device__ __forceinline__ float fmul_strict(float a, float b) {
    float r;
    asm volatile("v_mul_f32 %0, %1, %2" : "=v"(r) : "v"(a), "v"(b));
    return r;
}
__device__ __forceinline__ float fadd_strict(float a, float b) {
    float r;
    asm volatile("v_add_f32 %0, %1, %2" : "=v"(r) : "v"(a), "v"(b));
    return r;
}

__device__ __forceinline__ void lattice_point(
    const float* __restrict__ t,
    float p0, float p1, float p2,
    int& gi0, int& gi1, int& rc0, int& rc1)
{
    float e0 = fadd_strict(fadd_strict(fmul_strict(t[0], p0), fmul_strict(t[1], p1)), fmul_strict(t[2], p2));
    float e1 = fadd_strict(fadd_strict(fmul_strict(t[3], p0), fmul_strict(t[4], p1)), fmul_strict(t[5], p2));
    float e2 = fadd_strict(fadd_strict(fmul_strict(t[6], p0), fmul_strict(t[7], p1)), fmul_strict(t[8], p2));

    float g0 = __fmul_rn(rintf(__fmul_rn(e0, C3INV)), 3.0f);
    float g1 = __fmul_rn(rintf(__fmul_rn(e1, C3INV)), 3.0f);
    float g2 = __fmul_rn(rintf(__fmul_rn(e2, C3INV)), 3.0f);

    float m0 = e0 - g0, m1 = e1 - g1, m2 = e2 - g2;
    int r0 = (int)(m1 > m0) + (int)(m2 > m0);
    int r1 = (int)(m0 >= m1) + (int)(m2 > m1);

    gi0 = (int)g0;
    gi1 = (int)g1;

    const int irs = (gi0 + gi1 + (int)g2) / 3;

    if (irs > 0) {
        if (r0 >= 3 - irs) { gi0 -= 3; r0 -= 3; }
        if (r1 >= 3 - irs) { gi1 -= 3; r1 -= 3; }
    } else if (irs < 0) {
        if (r0 < -irs) { gi0 += 3; r0 += 3; }
        if (r1 < -irs) { gi1 += 3; r1 += 3; }
    }
    r0 += irs;
    r1 += irs;

    if (r0 < 0) r0 += 3;
    if (r1 < 0) r1 += 3;
    rc0 = min(2, max(0, r0));
    rc1 = min(2, max(0, r1));
}

// ceil(a/3) for any sign (exact)
__device__ __forceinline__ int icl3(int a) {
    return (a >= 0) ? (a + 2) / 3 : -((-a) / 3);
}

#define CH_HIST 16384   // 128*128 ints = 64 KB

// ===================== FUSED COOPERATIVE PATH (R18) =====================
// T2: per-dispatch overhead (~10us each) + graph-edge gaps dominate the
// remaining time (in-kernel roofline sums to ~25us vs 102 measured).
// One cooperative kernel, 384 blocks x 512 threads, 64KB LDS.
// __launch_bounds__(512,4): VGPR<=128 -> 2 blocks/CU (LDS-bound) ->
// 512 co-resident slots >= 384 launched, coop validation passes w/ margin.
//
// Phase 1: bin. bid -> (b = bid&31, s = bid>>5; s in 0..11). Slice s owns
//          float4-groups [s*1366, min(16384,(s+1)*1366)) of batch b.
// Phase 2: splat. s -> (ch = s>>2, chunk = s&3). Identical body to R17.
// Phase 3: sum+convert. Flat w = bid*512+tid < 32*4096. Identical body.
// __threadfence() before each grid.sync() for cross-XCD visibility.
#define FBLOCKS  384
#define FTHREADS 512
#define FSLICES  12
#define GRP_PER_B     (NPTS / 4)   // 16384 float4-groups per batch
#define GRP_PER_SLICE 1366         // ceil(16384/12); slice 11 gets 1358

__global__ __launch_bounds__(FTHREADS, 4) void fused_kernel(
    const float* __restrict__ pc, const float* __restrict__ feat,
    const float* __restrict__ tmg, uint32_t* __restrict__ bins,
    int* __restrict__ partial, int* __restrict__ stg, float* __restrict__ out)
{
    const int bid = blockIdx.x;
    const int tid = threadIdx.x;
    const int b   = bid & 31;       // batch fastest -> same-b blocks on one XCD
    const int s   = bid >> 5;       // 0..11

    __shared__ __align__(16) int ihist[CH_HIST];
    // Phase-1 aliases into the (not-yet-needed) histogram buffer:
    float* t_sh = (float*)ihist;    // ints [0..8]
    int*   r0   = ihist + 12;       // ints [12..19]
    int*   r1   = ihist + 24;       // ints [24..31]

    cg::grid_group grid = cg::this_grid();

    // ---------------- Phase 1: bin ----------------
    if (tid < 9) t_sh[tid] = tmg[b * 9 + tid];
    __syncthreads();

    const float* pcb = pc + (size_t)b * 3 * NPTS;
    int km0 = 0x7FFFFFFF, km1 = 0x7FFFFFFF;
    const int gbeg = s * GRP_PER_SLICE;
    const int gend = min(GRP_PER_B, gbeg + GRP_PER_SLICE);

    for (int v = gbeg + tid; v < gend; v += FTHREADS) {
        const float4 P0 = ((const float4*)(pcb + 0 * NPTS))[v];
        const float4 P1 = ((const float4*)(pcb + 1 * NPTS))[v];
        const float4 P2 = ((const float4*)(pcb + 2 * NPTS))[v];

        uint32_t pk[4];
        const float p0a[4] = {P0.x, P0.y, P0.z, P0.w};
        const float p1a[4] = {P1.x, P1.y, P1.z, P1.w};
        const float p2a[4] = {P2.x, P2.y, P2.z, P2.w};
#pragma unroll
        for (int i = 0; i < 4; ++i) {
            int gi0, gi1, rc0, rc1;
            lattice_point(t_sh, p0a[i], p1a[i], p2a[i], gi0, gi1, rc0, rc1);
            pk[i] = (uint32_t)(((gi0 / 3 + 512) << 16) | (gi1 / 3 + 512));
            km0 = min(km0, gi0 - rc0);
            km1 = min(km1, gi1 - rc1);
        }
        ((uint4*)(bins + (size_t)b * NPTS))[v] = make_uint4(pk[0], pk[1], pk[2], pk[3]);
    }

#pragma unroll
    for (int off = 32; off > 0; off >>= 1) {
        km0 = min(km0, __shfl_down(km0, off));
        km1 = min(km1, __shfl_down(km1, off));
    }
    if ((tid & 63) == 0) { r0[tid >> 6] = km0; r1[tid >> 6] = km1; }
    __syncthreads();
    if (tid == 0) {
        int m0 = r0[0], m1 = r1[0];
#pragma unroll
        for (int j = 1; j < FTHREADS / 64; ++j) { m0 = min(m0, r0[j]); m1 = min(m1, r1[j]); }
        partial[bid * 2 + 0] = m0;
        partial[bid * 2 + 1] = m1;
    }

    __threadfence();
    grid.sync();

    // ---------------- Phase 2: splat (LDS int histogram) ----------------
    const int ch    = s >> 2;   // 0..2
    const int chunk = s & 3;    // 0..3

#pragma unroll
    for (int j = 0; j < CH_HIST / 4 / FTHREADS; ++j)      // 8
        ((int4*)ihist)[j * FTHREADS + tid] = make_int4(0, 0, 0, 0);

    int off0 = 0x7FFFFFFF, off1 = 0x7FFFFFFF;
#pragma unroll
    for (int j = 0; j < FSLICES; ++j) {
        off0 = min(off0, partial[((j << 5) | b) * 2 + 0]);
        off1 = min(off1, partial[((j << 5) | b) * 2 + 1]);
    }
    __syncthreads();

    const int K0 = 512 + icl3(off0);
    const int K1 = 512 + icl3(off1);

    const uint32_t* bb = bins + (size_t)b * NPTS + (size_t)chunk * (NPTS / 4);
    const float*    fb = feat + ((size_t)b * 3 + ch) * NPTS + (size_t)chunk * (NPTS / 4);

    // 16384 points / 512 lanes / 4 per vector = 8 iterations
#pragma unroll
    for (int i = 0; i < (NPTS / 4) / (4 * FTHREADS); ++i) {
        const int v = i * FTHREADS + tid;
        const uint4  U = ((const uint4 *)bb)[v];
        const float4 F = ((const float4*)fb)[v];

        const uint32_t ua[4] = {U.x, U.y, U.z, U.w};
        const float    fa[4] = {F.x, F.y, F.z, F.w};

#pragma unroll
        for (int k = 0; k < 4; ++k) {
            const int y = (int)(ua[k] >> 16) - K0;   // >= 0 by construction
            const int x = (int)(ua[k] & 0xFFFFu) - K1;
            if (y < 128 && x < 128) {
                const int q = (int)rintf(__fmul_rn(fa[k], FP_SCALE));
                atomicAdd(&ihist[(y << 7) + x], q);   // native ds_add_u32
            }
        }
    }
    __syncthreads();

    // Flush: coalesced dwordx4 plain stores into private staging slice.
    int4* dst = (int4*)(stg + (size_t)(((b * 3 + ch) << 2) + chunk) * CH_HIST);
#pragma unroll
    for (int j = 0; j < CH_HIST / 4 / FTHREADS; ++j)
        dst[j * FTHREADS + tid] = ((const int4*)ihist)[j * FTHREADS + tid];

    __threadfence();
    grid.sync();

    // ---------------- Phase 3: sum chunks + convert ----------------
    const int w = bid * FTHREADS + tid;     // 0..196607
    if (w < NB * 4096) {
        const int b3 = w >> 12;
        const int t3 = w & 4095;

        float o[12];
#pragma unroll
        for (int c = 0; c < 3; ++c) {
            const int4* sp = (const int4*)(stg + (size_t)((b3 * 3 + c) << 2) * CH_HIST);
            const int4 a0 = sp[t3];
            const int4 a1 = sp[t3 + 1 * (CH_HIST / 4)];
            const int4 a2 = sp[t3 + 2 * (CH_HIST / 4)];
            const int4 a3 = sp[t3 + 3 * (CH_HIST / 4)];
            const int vx = a0.x + a1.x + a2.x + a3.x;
            const int vy = a0.y + a1.y + a2.y + a3.y;
            const int vz = a0.z + a1.z + a2.z + a3.z;
            const int vw = a0.w + a1.w + a2.w + a3.w;
            o[0 * 3 + c] = __fmul_rn((float)vx, FP_INV);
            o[1 * 3 + c] = __fmul_rn((float)vy, FP_INV);
            o[2 * 3 + c] = __fmul_rn((float)vz, FP_INV);
            o[3 * 3 + c] = __fmul_rn((float)vw, FP_INV);
        }

        float4* op = (float4*)(out + ((size_t)((b3 << 14) + t3 * 4)) * 3);
        op[0] = make_float4(o[0], o[1],  o[2],  o[3]);
        op[1] = make_float4(o[4], o[5],  o[6],  o[7]);
        op[2] = make_float4(o[8], o[9],  o[10], o[11]);
    }
}

// ==================== 3-DISPATCH PATH (R17, verified) ====================
__global__ __launch_bounds__(1024) void bin_kernel(
    const float* __restrict__ pc, const float* __restrict__ tmg,
    uint32_t* __restrict__ bins, int* __restrict__ partial)
{
    const int bx  = blockIdx.x;   // 0..15
    const int b   = blockIdx.y;
    const int tid = threadIdx.x;

    __shared__ float t[9];
    if (tid < 9) t[tid] = tmg[b * 9 + tid];
    __syncthreads();

    const float* pcb = pc + (size_t)b * 3 * NPTS;
    const int v = bx * 1024 + tid;           // float4 group index

    const float4 P0 = ((const float4*)(pcb + 0 * NPTS))[v];
    const float4 P1 = ((const float4*)(pcb + 1 * NPTS))[v];
    const float4 P2 = ((const float4*)(pcb + 2 * NPTS))[v];

    int km0 = 0x7FFFFFFF, km1 = 0x7FFFFFFF;
    uint32_t pk[4];
    const float p0a[4] = {P0.x, P0.y, P0.z, P0.w};
    const float p1a[4] = {P1.x, P1.y, P1.z, P1.w};
    const float p2a[4] = {P2.x, P2.y, P2.z, P2.w};
#pragma unroll
    for (int i = 0; i < 4; ++i) {
        int gi0, gi1, rc0, rc1;
        lattice_point(t, p0a[i], p1a[i], p2a[i], gi0, gi1, rc0, rc1);
        pk[i] = (uint32_t)(((gi0 / 3 + 512) << 16) | (gi1 / 3 + 512));
        km0 = min(km0, gi0 - rc0);
        km1 = min(km1, gi1 - rc1);
    }
    ((uint4*)(bins + (size_t)b * NPTS))[v] = make_uint4(pk[0], pk[1], pk[2], pk[3]);

#pragma unroll
    for (int off = 32; off > 0; off >>= 1) {
        km0 = min(km0, __shfl_down(km0, off));
        km1 = min(km1, __shfl_down(km1, off));
    }
    __shared__ int s0[16], s1[16];
    if ((tid & 63) == 0) { s0[tid >> 6] = km0; s1[tid >> 6] = km1; }
    __syncthreads();
    if (tid == 0) {
        int m0 = s0[0], m1 = s1[0];
#pragma unroll
        for (int j = 1; j < 16; ++j) { m0 = min(m0, s0[j]); m1 = min(m1, s1[j]); }
        partial[(b * 16 + bx) * 2 + 0] = m0;
        partial[(b * 16 + bx) * 2 + 1] = m1;
    }
}

__global__ __launch_bounds__(1024) void splat_ch_stage_kernel(
    const uint32_t* __restrict__ bins, const float* __restrict__ feat,
    const int* __restrict__ partial, int* __restrict__ stg)
{
    const int b     = blockIdx.x;
    const int ch    = blockIdx.y;
    const int chunk = blockIdx.z;
    const int tid   = threadIdx.x;

    __shared__ __align__(16) int ihist[CH_HIST];
#pragma unroll
    for (int j = 0; j < 4; ++j)
        ((int4*)ihist)[j * 1024 + tid] = make_int4(0, 0, 0, 0);

    int off0 = 0x7FFFFFFF, off1 = 0x7FFFFFFF;
#pragma unroll
    for (int j = 0; j < 16; ++j) {
        off0 = min(off0, partial[(b * 16 + j) * 2 + 0]);
        off1 = min(off1, partial[(b * 16 + j) * 2 + 1]);
    }
    __syncthreads();

    const int K0 = 512 + icl3(off0);
    const int K1 = 512 + icl3(off1);

    const uint32_t* bb = bins + (size_t)b * NPTS + (size_t)chunk * (NPTS / 4);
    const float*    fb = feat + ((size_t)b * 3 + ch) * NPTS + (size_t)chunk * (NPTS / 4);

#pragma unroll
    for (int i = 0; i < (NPTS / 4) / 4096; ++i) {
        const int v = i * 1024 + tid;
        const uint4  U = ((const uint4 *)bb)[v];
        const float4 F = ((const float4*)fb)[v];

        const uint32_t ua[4] = {U.x, U.y, U.z, U.w};
        const float    fa[4] = {F.x, F.y, F.z, F.w};

#pragma unroll
        for (int k = 0; k < 4; ++k) {
            const int y = (int)(ua[k] >> 16) - K0;
            const int x = (int)(ua[k] & 0xFFFFu) - K1;
            if (y < 128 && x < 128) {
                const int q = (int)rintf(__fmul_rn(fa[k], FP_SCALE));
                atomicAdd(&ihist[(y << 7) + x], q);
            }
        }
    }
    __syncthreads();

    int4* dst = (int4*)(stg + (size_t)(((b * 3 + ch) << 2) + chunk) * CH_HIST);
#pragma unroll
    for (int j = 0; j < 4; ++j)
        dst[j * 1024 + tid] = ((const int4*)ihist)[j * 1024 + tid];
}

__global__ __launch_bounds__(1024) void sum_convert_kernel(
    const int* __restrict__ stg, float* __restrict__ out)
{
    const int t = blockIdx.x * 1024 + threadIdx.x;
    const int b = blockIdx.y;

    float o[12];
#pragma unroll
    for (int ch = 0; ch < 3; ++ch) {
        const int4* s = (const int4*)(stg + (size_t)((b * 3 + ch) << 2) * CH_HIST);
        const int4 a0 = s[t];
        const int4 a1 = s[t + 1 * (CH_HIST / 4)];
        const int4 a2 = s[t + 2 * (CH_HIST / 4)];
        const int4 a3 = s[t + 3 * (CH_HIST / 4)];
        const int vx = a0.x + a1.x + a2.x + a3.x;
        const int vy = a0.y + a1.y + a2.y + a3.y;
        const int vz = a0.z + a1.z + a2.z + a3.z;
        const int vw = a0.w + a1.w + a2.w + a3.w;
        o[0 * 3 + ch] = __fmul_rn((float)vx, FP_INV);
        o[1 * 3 + ch] = __fmul_rn((float)vy, FP_INV);
        o[2 * 3 + ch] = __fmul_rn((float)vz, FP_INV);
        o[3 * 3 + ch] = __fmul_rn((float)vw, FP_INV);
    }

    float4* op = (float4*)(out + ((size_t)((b << 14) + t * 4)) * 3);
    op[0] = make_float4(o[0], o[1],  o[2],  o[3]);
    op[1] = make_float4(o[4], o[5],  o[6],  o[7]);
    op[2] = make_float4(o[8], o[9],  o[10], o[11]);
}

// ---- Middle tier (R16): global-atomic flush ----
__global__ __launch_bounds__(1024) void splat_ch_int_kernel(
    const uint32_t* __restrict__ bins, const float* __restrict__ feat,
    const int* __restrict__ partial, int* __restrict__ iout)
{
    const int b     = blockIdx.x;
    const int ch    = blockIdx.y;
    const int chunk = blockIdx.z;
    const int tid   = threadIdx.x;

    __shared__ int ihist[CH_HIST];
#pragma unroll
    for (int i = tid; i < CH_HIST; i += 1024) ihist[i] = 0;

    int off0 = 0x7FFFFFFF, off1 = 0x7FFFFFFF;
#pragma unroll
    for (int j = 0; j < 16; ++j) {
        off0 = min(off0, partial[(b * 16 + j) * 2 + 0]);
        off1 = min(off1, partial[(b * 16 + j) * 2 + 1]);
    }
    __syncthreads();

    const int K0 = 512 + icl3(off0);
    const int K1 = 512 + icl3(off1);

    const uint32_t* bb = bins + (size_t)b * NPTS + (size_t)chunk * (NPTS / 4);
    const float*    fb = feat + ((size_t)b * 3 + ch) * NPTS + (size_t)chunk * (NPTS / 4);

#pragma unroll
    for (int i = 0; i < (NPTS / 4) / 4096; ++i) {
        const int v = i * 1024 + tid;
        const uint4  U = ((const uint4 *)bb)[v];
        const float4 F = ((const float4*)fb)[v];
        const uint32_t ua[4] = {U.x, U.y, U.z, U.w};
        const float    fa[4] = {F.x, F.y, F.z, F.w};
#pragma unroll
        for (int k = 0; k < 4; ++k) {
            const int y = (int)(ua[k] >> 16) - K0;
            const int x = (int)(ua[k] & 0xFFFFu) - K1;
            if (y < 128 && x < 128) {
                const int q = (int)rintf(__fmul_rn(fa[k], FP_SCALE));
                atomicAdd(&ihist[(y << 7) + x], q);
            }
        }
    }
    __syncthreads();

#pragma unroll
    for (int i = tid; i < CH_HIST; i += 1024) {
        const int v = ihist[i];
        if (v != 0) atomicAdd(&iout[(size_t)((b << 14) + i) * 3 + ch], v);
    }
}

__global__ __launch_bounds__(1024) void convert_kernel(float* __restrict__ out)
{
    const int i = blockIdx.x * 1024 + threadIdx.x;
    const int v = ((const int*)out)[i];
    out[i] = __fmul_rn((float)v, FP_INV);
}

// ========================= FALLBACK PATH ==========================
#define FTILE_X 16
#define FHIST_F (128 * FTILE_X * 3)

__global__ __launch_bounds__(1024) void kmin2_kernel(
    const float* __restrict__ pc, const float* __restrict__ tmg,
    int* __restrict__ mins)
{
    const int b = blockIdx.y, bx = blockIdx.x, tid = threadIdx.x;
    __shared__ float t[9];
    if (tid < 9) t[tid] = tmg[b * 9 + tid];
    __syncthreads();

    const float* pcb = pc + (size_t)b * 3 * NPTS;
    int km0 = 0x7FFFFFFF, km1 = 0x7FFFFFFF;
    const int n0 = bx * 8192;
#pragma unroll
    for (int i = 0; i < 8; ++i) {
        const int n = n0 + i * 1024 + tid;
        int gi0, gi1, rc0, rc1;
        lattice_point(t, pcb[n], pcb[NPTS + n], pcb[2 * NPTS + n], gi0, gi1, rc0, rc1);
        km0 = min(km0, gi0 - rc0);
        km1 = min(km1, gi1 - rc1);
    }
#pragma unroll
    for (int off = 32; off > 0; off >>= 1) {
        km0 = min(km0, __shfl_down(km0, off));
        km1 = min(km1, __shfl_down(km1, off));
    }
    __shared__ int s0[16], s1[16];
    if ((tid & 63) == 0) { s0[tid >> 6] = km0; s1[tid >> 6] = km1; }
    __syncthreads();
    if (tid == 0) {
        int m0 = s0[0], m1 = s1[0];
#pragma unroll
        for (int j = 1; j < 16; ++j) { m0 = min(m0, s0[j]); m1 = min(m1, s1[j]); }
        atomicMin(&mins[b * 2 + 0], m0);
        atomicMin(&mins[b * 2 + 1], m1);
    }
}

__global__ __launch_bounds__(1024) void splat_recompute_kernel(
    const float* __restrict__ pc, const float* __restrict__ feat,
    const float* __restrict__ tmg, const int* __restrict__ mins,
    float* __restrict__ out)
{
    const int tile = blockIdx.x, b = blockIdx.y, tid = threadIdx.x;
    const int x0 = tile * FTILE_X;

    __shared__ float t[9];
    __shared__ float hist[FHIST_F];
    if (tid < 9) t[tid] = tmg[b * 9 + tid];
#pragma unroll
    for (int i = tid; i < FHIST_F; i += 1024) hist[i] = 0.0f;
    __syncthreads();

    const int off0 = mins[b * 2 + 0];
    const int off1 = mins[b * 2 + 1];
    const float* pcb = pc + (size_t)b * 3 * NPTS;
    const float* ftb = feat + (size_t)b * 3 * NPTS;

    for (int n = tid; n < NPTS; n += 1024) {
        int gi0, gi1, rc0, rc1;
        lattice_point(t, pcb[n], pcb[NPTS + n], pcb[2 * NPTS + n], gi0, gi1, rc0, rc1);
        const int c0 = gi0 - off0;
        const int c1 = gi1 - off1;
        if ((unsigned)c0 < SS && (unsigned)c1 < SS) {
            const int x = c1 / 3;
            if ((x >> 4) == tile) {
                const int y = c0 / 3;
                const int base = (y * FTILE_X + (x - x0)) * 3;
                atomicAdd(&hist[base + 0], ftb[0 * NPTS + n]);
                atomicAdd(&hist[base + 1], ftb[1 * NPTS + n]);
                atomicAdd(&hist[base + 2], ftb[2 * NPTS + n]);
            }
        }
    }
    __syncthreads();
#pragma unroll
    for (int idx = tid; idx < FHIST_F; idx += 1024) {
        const int y   = idx / (FTILE_X * 3);
        const int rem = idx - y * (FTILE_X * 3);
        out[(size_t)(b * 128 + y) * 384 + x0 * 3 + rem] = hist[idx];
    }
}

extern "C" void kernel_launch(void* const* d_in, const int* in_sizes, int n_in,
                              void* d_out, int out_size, void* d_ws, size_t ws_size,
                              hipStream_t stream) {
    const float* pc   = (const float*)d_in[0];  // (32,3,65536) f32
    const float* feat = (const float*)d_in[1];  // (32,3,65536) f32
    const float* tm   = (const float*)d_in[2];  // (32,3,3) f32
    float* out = (float*)d_out;                 // (32,128,128,3) f32

    const size_t bins_bytes = (size_t)NB * NPTS * sizeof(uint32_t);        // 8 MB
    const size_t part_bytes = 4096;                                        // >= 384*2 ints
    const size_t stg_bytes  = (size_t)NB * 3 * 4 * CH_HIST * sizeof(int);  // 25.2 MB
    const size_t need_full  = bins_bytes + part_bytes + stg_bytes;

    // One-time cooperative-launch capability check (host query, capture-safe).
    static int coop_ok = -1;
    if (coop_ok < 0) {
        int dev = 0;
        hipDeviceProp_t prop;
        if (hipGetDevice(&dev) == hipSuccess &&
            hipGetDeviceProperties(&prop, dev) == hipSuccess)
            coop_ok = prop.cooperativeLaunch ? 1 : 0;
        else
            coop_ok = 0;
    }

    if (coop_ok == 1 && ws_size >= need_full) {
        // R18: single cooperative dispatch (bin -> splat -> sum/convert).
        uint32_t* bins = (uint32_t*)d_ws;
        int* partial = (int*)((char*)d_ws + bins_bytes);
        int* stg     = (int*)((char*)d_ws + bins_bytes + part_bytes);

        const float* a_pc = pc; const float* a_feat = feat; const float* a_tm = tm;
        uint32_t* a_bins = bins; int* a_partial = partial; int* a_stg = stg;
        float* a_out = out;
        void* args[] = {&a_pc, &a_feat, &a_tm, &a_bins, &a_partial, &a_stg, &a_out};

        hipError_t e = hipLaunchCooperativeKernel(
            (const void*)fused_kernel, dim3(FBLOCKS), dim3(FTHREADS),
            args, 0, stream);
        if (e == hipSuccess) return;
        coop_ok = 0;   // fall through to the verified 3-dispatch path
    }

    if (ws_size >= need_full) {
        // R17 path (verified): 3 dispatches, no global atomics.
        uint32_t* bins = (uint32_t*)d_ws;
        int* partial = (int*)((char*)d_ws + bins_bytes);
        int* stg     = (int*)((char*)d_ws + bins_bytes + part_bytes);

        dim3 gridA(16, NB);
        bin_kernel<<<gridA, 1024, 0, stream>>>(pc, tm, bins, partial);
        dim3 gridB(NB, 3, 4);
        splat_ch_stage_kernel<<<gridB, 1024, 0, stream>>>(bins, feat, partial, stg);
        dim3 gridC(4, NB);
        sum_convert_kernel<<<gridC, 1024, 0, stream>>>(stg, out);
    } else if (ws_size >= bins_bytes + part_bytes) {
        // R16 path (verified): global-atomic flush + convert.
        uint32_t* bins = (uint32_t*)d_ws;
        int* partial = (int*)((char*)d_ws + bins_bytes);

        hipMemsetAsync(out, 0, (size_t)out_size * sizeof(float), stream);

        dim3 gridA(16, NB);
        bin_kernel<<<gridA, 1024, 0, stream>>>(pc, tm, bins, partial);
        dim3 gridB(NB, 3, 4);
        splat_ch_int_kernel<<<gridB, 1024, 0, stream>>>(bins, feat, partial, (int*)out);
        convert_kernel<<<(out_size + 1023) / 1024, 1024, 0, stream>>>(out);
    } else {
        int* mins = (int*)d_ws;  // 64 ints
        hipMemsetAsync(mins, 0x7F, 64 * sizeof(int), stream);
        dim3 grid(8, NB);
        kmin2_kernel<<<grid, 1024, 0, stream>>>(pc, tm, mins);
        dim3 gridB2(8, NB);
        splat_recompute_kernel<<<gridB2, 1024, 0, stream>>>(pc, feat, tm, mins, out);
    }
}

// Round 3
// 178.441 us; speedup vs baseline: 1.9752x; 1.9752x over previous
//
#include <hip/hip_runtime.h>
#include <stdint.h>

// Problem constants (from reference): D1=3, S=384, B=32, N=65536
#define NPTS 65536
#define NB   32
#define SS   384

// RN(1/3) in f32 = 0x3EAAAAAB
#define C3INV 0.333333343267440796f

// Fixed-point scale for histogram accumulation (R16): int LDS atomics emit a
// single native ds_add_u32. |bin sum| < ~65k -> scale 2^15 fits int32 with
// margin; quantization ~1.5e-5/add, worst bin ~6e-3 << 0.5 threshold.
#define FP_SCALE 32768.0f
#define FP_INV   (1.0f / 32768.0f)

// ---- LOCKED NUMERICS (R7, passed absmax<=0.0156) ----
__device__ __forceinline__ float fmul_strict(float a, float b) {
    float r;
    asm volatile("v_mul_f32 %0, %1, %2" : "=v"(r) : "v"(a), "v"(b));
    return r;
}
__device__ __forceinline__ float fadd_strict(float a, float b) {
    float r;
    asm volatile("v_add_f32 %0, %1, %2" : "=v"(r) : "v"(a), "v"(b));
    return r;
}

__device__ __forceinline__ void lattice_point(
    const float* __restrict__ t,
    float p0, float p1, float p2,
    int& gi0, int& gi1, int& rc0, int& rc1)
{
    float e0 = fadd_strict(fadd_strict(fmul_strict(t[0], p0), fmul_strict(t[1], p1)), fmul_strict(t[2], p2));
    float e1 = fadd_strict(fadd_strict(fmul_strict(t[3], p0), fmul_strict(t[4], p1)), fmul_strict(t[5], p2));
    float e2 = fadd_strict(fadd_strict(fmul_strict(t[6], p0), fmul_strict(t[7], p1)), fmul_strict(t[8], p2));

    float g0 = __fmul_rn(rintf(__fmul_rn(e0, C3INV)), 3.0f);
    float g1 = __fmul_rn(rintf(__fmul_rn(e1, C3INV)), 3.0f);
    float g2 = __fmul_rn(rintf(__fmul_rn(e2, C3INV)), 3.0f);

    float m0 = e0 - g0, m1 = e1 - g1, m2 = e2 - g2;
    int r0 = (int)(m1 > m0) + (int)(m2 > m0);
    int r1 = (int)(m0 >= m1) + (int)(m2 > m1);

    gi0 = (int)g0;
    gi1 = (int)g1;

    const int irs = (gi0 + gi1 + (int)g2) / 3;

    if (irs > 0) {
        if (r0 >= 3 - irs) { gi0 -= 3; r0 -= 3; }
        if (r1 >= 3 - irs) { gi1 -= 3; r1 -= 3; }
    } else if (irs < 0) {
        if (r0 < -irs) { gi0 += 3; r0 += 3; }
        if (r1 < -irs) { gi1 += 3; r1 += 3; }
    }
    r0 += irs;
    r1 += irs;

    if (r0 < 0) r0 += 3;
    if (r1 < 0) r1 += 3;
    rc0 = min(2, max(0, r0));
    rc1 = min(2, max(0, r1));
}

// ceil(a/3) for any sign (exact)
__device__ __forceinline__ int icl3(int a) {
    return (a >= 0) ? (a + 2) / 3 : -((-a) / 3);
}

#define CH_HIST 16384   // 128*128 ints = 64 KB

// ============================ FAST PATH (R19) ============================
// 2 dispatches. R18 post-mortem: grid-wide cg::sync costs ~100us/sync on
// 8 non-coherent XCDs (fused kernel 95% idle) -> disqualified. Instead,
// fuse the chunk-sum + convert into the splat kernel via a device-side
// "last block finalizes" ticket (no spinning: losers exit; exactly one
// winner per (b,ch) sums the 4 staged slices and writes out directly).

// Kernel A: float4 pc loads (4 points/lane), uint4 bins store.
// Also zeroes the 96 finalize tickets (ws is re-poisoned between iters).
__global__ __launch_bounds__(1024) void bin_kernel(
    const float* __restrict__ pc, const float* __restrict__ tmg,
    uint32_t* __restrict__ bins, int* __restrict__ partial,
    int* __restrict__ tickets)
{
    const int bx  = blockIdx.x;   // 0..15
    const int b   = blockIdx.y;
    const int tid = threadIdx.x;

    if (bx == 0 && tid < 3) tickets[b * 3 + tid] = 0;

    __shared__ float t[9];
    if (tid < 9) t[tid] = tmg[b * 9 + tid];
    __syncthreads();

    const float* pcb = pc + (size_t)b * 3 * NPTS;
    const int v = bx * 1024 + tid;           // float4 group index

    const float4 P0 = ((const float4*)(pcb + 0 * NPTS))[v];
    const float4 P1 = ((const float4*)(pcb + 1 * NPTS))[v];
    const float4 P2 = ((const float4*)(pcb + 2 * NPTS))[v];

    int km0 = 0x7FFFFFFF, km1 = 0x7FFFFFFF;
    uint32_t pk[4];
    const float p0a[4] = {P0.x, P0.y, P0.z, P0.w};
    const float p1a[4] = {P1.x, P1.y, P1.z, P1.w};
    const float p2a[4] = {P2.x, P2.y, P2.z, P2.w};
#pragma unroll
    for (int i = 0; i < 4; ++i) {
        int gi0, gi1, rc0, rc1;
        lattice_point(t, p0a[i], p1a[i], p2a[i], gi0, gi1, rc0, rc1);
        pk[i] = (uint32_t)(((gi0 / 3 + 512) << 16) | (gi1 / 3 + 512));
        km0 = min(km0, gi0 - rc0);
        km1 = min(km1, gi1 - rc1);
    }
    ((uint4*)(bins + (size_t)b * NPTS))[v] = make_uint4(pk[0], pk[1], pk[2], pk[3]);

#pragma unroll
    for (int off = 32; off > 0; off >>= 1) {
        km0 = min(km0, __shfl_down(km0, off));
        km1 = min(km1, __shfl_down(km1, off));
    }
    __shared__ int s0[16], s1[16];
    if ((tid & 63) == 0) { s0[tid >> 6] = km0; s1[tid >> 6] = km1; }
    __syncthreads();
    if (tid == 0) {
        int m0 = s0[0], m1 = s1[0];
#pragma unroll
        for (int j = 1; j < 16; ++j) { m0 = min(m0, s0[j]); m1 = min(m1, s1[j]); }
        partial[(b * 16 + bx) * 2 + 0] = m0;
        partial[(b * 16 + bx) * 2 + 1] = m1;
    }
}

// Kernel B (R19): splat + device-side finalize.
// Grid (b=32 fastest, ch=3, chunk=4): all 12 blocks of batch b share
// linear%8 == b%8 -> one XCD -> staging slices are L2-hot for the
// finalizer, and plain-store/fence/atomic visibility is L2-local (the
// __threadfence device-scope wb/inv still covers a cross-XCD schedule).
__global__ __launch_bounds__(1024) void splat_finalize_kernel(
    const uint32_t* __restrict__ bins, const float* __restrict__ feat,
    const int* __restrict__ partial, int* __restrict__ tickets,
    int* __restrict__ stg, float* __restrict__ out)
{
    const int b     = blockIdx.x;     // 0..31 (fastest -> XCD co-location)
    const int ch    = blockIdx.y;     // 0..2
    const int chunk = blockIdx.z;     // 0..3
    const int tid   = threadIdx.x;    // 0..1023

    __shared__ __align__(16) int ihist[CH_HIST];
#pragma unroll
    for (int j = 0; j < 4; ++j)
        ((int4*)ihist)[j * 1024 + tid] = make_int4(0, 0, 0, 0);

    int off0 = 0x7FFFFFFF, off1 = 0x7FFFFFFF;
#pragma unroll
    for (int j = 0; j < 16; ++j) {
        off0 = min(off0, partial[(b * 16 + j) * 2 + 0]);
        off1 = min(off1, partial[(b * 16 + j) * 2 + 1]);
    }
    __syncthreads();

    // y = s0 - ceil(off0/3), x = s1 - ceil(off1/3)  (exact; >= 0)
    const int K0 = 512 + icl3(off0);
    const int K1 = 512 + icl3(off1);

    const uint32_t* bb = bins + (size_t)b * NPTS + (size_t)chunk * (NPTS / 4);
    const float*    fb = feat + ((size_t)b * 3 + ch) * NPTS + (size_t)chunk * (NPTS / 4);

    // 16384 points / 1024 lanes / 4 per vector = 4 iterations
#pragma unroll
    for (int i = 0; i < (NPTS / 4) / 4096; ++i) {
        const int v = i * 1024 + tid;
        const uint4  U = ((const uint4 *)bb)[v];
        const float4 F = ((const float4*)fb)[v];

        const uint32_t ua[4] = {U.x, U.y, U.z, U.w};
        const float    fa[4] = {F.x, F.y, F.z, F.w};

#pragma unroll
        for (int k = 0; k < 4; ++k) {
            const int y = (int)(ua[k] >> 16) - K0;   // >= 0 by construction
            const int x = (int)(ua[k] & 0xFFFFu) - K1;
            if (y < 128 && x < 128) {
                const int q = (int)rintf(__fmul_rn(fa[k], FP_SCALE));
                atomicAdd(&ihist[(y << 7) + x], q);   // native ds_add_u32
            }
        }
    }
    __syncthreads();

    // Flush own slice: ds_read_b128 + global_store_dwordx4, coalesced.
    int* slice_base = stg + ((size_t)(b * 3 + ch) * 4 + chunk) * CH_HIST;
    int4* dst = (int4*)slice_base;
#pragma unroll
    for (int j = 0; j < 4; ++j)
        dst[j * 1024 + tid] = ((const int4*)ihist)[j * 1024 + tid];

    // __syncthreads drains each thread's vmcnt (compiler emits
    // s_waitcnt vmcnt(0) before s_barrier) -> all block stores are in L2.
    __syncthreads();

    __shared__ int lastFlag;
    if (tid == 0) {
        __threadfence();                               // release: L2 wb
        const int old = atomicAdd(&tickets[b * 3 + ch], 1);  // device scope
        lastFlag = (old == 3);
    }
    __syncthreads();
    if (!lastFlag) return;

    // ---- Finalizer: exactly one block per (b,ch) ----
    __threadfence();                                   // acquire: L2 inv

    const int4* sl0 = (const int4*)(stg + ((size_t)(b * 3 + ch) * 4 + 0) * CH_HIST);
    const int4* sl1 = (const int4*)(stg + ((size_t)(b * 3 + ch) * 4 + 1) * CH_HIST);
    const int4* sl2 = (const int4*)(stg + ((size_t)(b * 3 + ch) * 4 + 2) * CH_HIST);
    const int4* sl3 = (const int4*)(stg + ((size_t)(b * 3 + ch) * 4 + 3) * CH_HIST);

#pragma unroll
    for (int j = 0; j < 4; ++j) {
        const int t = j * 1024 + tid;                  // int4-group 0..4095
        const int4 a0 = sl0[t];
        const int4 a1 = sl1[t];
        const int4 a2 = sl2[t];
        const int4 a3 = sl3[t];
        // int sum: associative, order-free -> bit-identical to R17 path
        const int vx = a0.x + a1.x + a2.x + a3.x;
        const int vy = a0.y + a1.y + a2.y + a3.y;
        const int vz = a0.z + a1.z + a2.z + a3.z;
        const int vw = a0.w + a1.w + a2.w + a3.w;

        // out[(b*16384 + cell)*3 + ch], cell = 4t..4t+3 (stride-12B dword
        // stores; the 3 ch-finalizers of b merge lines in the shared L2)
        float* op = out + ((size_t)((b << 14) + t * 4)) * 3 + ch;
        op[0] = __fmul_rn((float)vx, FP_INV);
        op[3] = __fmul_rn((float)vy, FP_INV);
        op[6] = __fmul_rn((float)vz, FP_INV);
        op[9] = __fmul_rn((float)vw, FP_INV);
    }
}

// ---- Middle tier (R16, verified): global-atomic flush + convert ----
__global__ __launch_bounds__(1024) void splat_ch_int_kernel(
    const uint32_t* __restrict__ bins, const float* __restrict__ feat,
    const int* __restrict__ partial, int* __restrict__ iout)
{
    const int b     = blockIdx.x;
    const int ch    = blockIdx.y;
    const int chunk = blockIdx.z;
    const int tid   = threadIdx.x;

    __shared__ int ihist[CH_HIST];
#pragma unroll
    for (int i = tid; i < CH_HIST; i += 1024) ihist[i] = 0;

    int off0 = 0x7FFFFFFF, off1 = 0x7FFFFFFF;
#pragma unroll
    for (int j = 0; j < 16; ++j) {
        off0 = min(off0, partial[(b * 16 + j) * 2 + 0]);
        off1 = min(off1, partial[(b * 16 + j) * 2 + 1]);
    }
    __syncthreads();

    const int K0 = 512 + icl3(off0);
    const int K1 = 512 + icl3(off1);

    const uint32_t* bb = bins + (size_t)b * NPTS + (size_t)chunk * (NPTS / 4);
    const float*    fb = feat + ((size_t)b * 3 + ch) * NPTS + (size_t)chunk * (NPTS / 4);

#pragma unroll
    for (int i = 0; i < (NPTS / 4) / 4096; ++i) {
        const int v = i * 1024 + tid;
        const uint4  U = ((const uint4 *)bb)[v];
        const float4 F = ((const float4*)fb)[v];
        const uint32_t ua[4] = {U.x, U.y, U.z, U.w};
        const float    fa[4] = {F.x, F.y, F.z, F.w};
#pragma unroll
        for (int k = 0; k < 4; ++k) {
            const int y = (int)(ua[k] >> 16) - K0;
            const int x = (int)(ua[k] & 0xFFFFu) - K1;
            if (y < 128 && x < 128) {
                const int q = (int)rintf(__fmul_rn(fa[k], FP_SCALE));
                atomicAdd(&ihist[(y << 7) + x], q);
            }
        }
    }
    __syncthreads();

#pragma unroll
    for (int i = tid; i < CH_HIST; i += 1024) {
        const int v = ihist[i];
        if (v != 0) atomicAdd(&iout[(size_t)((b << 14) + i) * 3 + ch], v);
    }
}

__global__ __launch_bounds__(1024) void convert_kernel(float* __restrict__ out)
{
    const int i = blockIdx.x * 1024 + threadIdx.x;
    const int v = ((const int*)out)[i];
    out[i] = __fmul_rn((float)v, FP_INV);
}

// ========================= FALLBACK PATH ==========================
#define FTILE_X 16
#define FHIST_F (128 * FTILE_X * 3)

__global__ __launch_bounds__(1024) void kmin2_kernel(
    const float* __restrict__ pc, const float* __restrict__ tmg,
    int* __restrict__ mins)
{
    const int b = blockIdx.y, bx = blockIdx.x, tid = threadIdx.x;
    __shared__ float t[9];
    if (tid < 9) t[tid] = tmg[b * 9 + tid];
    __syncthreads();

    const float* pcb = pc + (size_t)b * 3 * NPTS;
    int km0 = 0x7FFFFFFF, km1 = 0x7FFFFFFF;
    const int n0 = bx * 8192;
#pragma unroll
    for (int i = 0; i < 8; ++i) {
        const int n = n0 + i * 1024 + tid;
        int gi0, gi1, rc0, rc1;
        lattice_point(t, pcb[n], pcb[NPTS + n], pcb[2 * NPTS + n], gi0, gi1, rc0, rc1);
        km0 = min(km0, gi0 - rc0);
        km1 = min(km1, gi1 - rc1);
    }
#pragma unroll
    for (int off = 32; off > 0; off >>= 1) {
        km0 = min(km0, __shfl_down(km0, off));
        km1 = min(km1, __shfl_down(km1, off));
    }
    __shared__ int s0[16], s1[16];
    if ((tid & 63) == 0) { s0[tid >> 6] = km0; s1[tid >> 6] = km1; }
    __syncthreads();
    if (tid == 0) {
        int m0 = s0[0], m1 = s1[0];
#pragma unroll
        for (int j = 1; j < 16; ++j) { m0 = min(m0, s0[j]); m1 = min(m1, s1[j]); }
        atomicMin(&mins[b * 2 + 0], m0);
        atomicMin(&mins[b * 2 + 1], m1);
    }
}

__global__ __launch_bounds__(1024) void splat_recompute_kernel(
    const float* __restrict__ pc, const float* __restrict__ feat,
    const float* __restrict__ tmg, const int* __restrict__ mins,
    float* __restrict__ out)
{
    const int tile = blockIdx.x, b = blockIdx.y, tid = threadIdx.x;
    const int x0 = tile * FTILE_X;

    __shared__ float t[9];
    __shared__ float hist[FHIST_F];
    if (tid < 9) t[tid] = tmg[b * 9 + tid];
#pragma unroll
    for (int i = tid; i < FHIST_F; i += 1024) hist[i] = 0.0f;
    __syncthreads();

    const int off0 = mins[b * 2 + 0];
    const int off1 = mins[b * 2 + 1];
    const float* pcb = pc + (size_t)b * 3 * NPTS;
    const float* ftb = feat + (size_t)b * 3 * NPTS;

    for (int n = tid; n < NPTS; n += 1024) {
        int gi0, gi1, rc0, rc1;
        lattice_point(t, pcb[n], pcb[NPTS + n], pcb[2 * NPTS + n], gi0, gi1, rc0, rc1);
        const int c0 = gi0 - off0;
        const int c1 = gi1 - off1;
        if ((unsigned)c0 < SS && (unsigned)c1 < SS) {
            const int x = c1 / 3;
            if ((x >> 4) == tile) {
                const int y = c0 / 3;
                const int base = (y * FTILE_X + (x - x0)) * 3;
                atomicAdd(&hist[base + 0], ftb[0 * NPTS + n]);
                atomicAdd(&hist[base + 1], ftb[1 * NPTS + n]);
                atomicAdd(&hist[base + 2], ftb[2 * NPTS + n]);
            }
        }
    }
    __syncthreads();
#pragma unroll
    for (int idx = tid; idx < FHIST_F; idx += 1024) {
        const int y   = idx / (FTILE_X * 3);
        const int rem = idx - y * (FTILE_X * 3);
        out[(size_t)(b * 128 + y) * 384 + x0 * 3 + rem] = hist[idx];
    }
}

extern "C" void kernel_launch(void* const* d_in, const int* in_sizes, int n_in,
                              void* d_out, int out_size, void* d_ws, size_t ws_size,
                              hipStream_t stream) {
    const float* pc   = (const float*)d_in[0];  // (32,3,65536) f32
    const float* feat = (const float*)d_in[1];  // (32,3,65536) f32
    const float* tm   = (const float*)d_in[2];  // (32,3,3) f32
    float* out = (float*)d_out;                 // (32,128,128,3) f32

    const size_t bins_bytes = (size_t)NB * NPTS * sizeof(uint32_t);        // 8 MB
    const size_t part_bytes = 4096;                                        // 1024 ints
    const size_t tick_bytes = 512;                                         // 96 ints
    const size_t stg_bytes  = (size_t)NB * 3 * 4 * CH_HIST * sizeof(int);  // 25.2 MB
    const size_t need_full  = bins_bytes + part_bytes + tick_bytes + stg_bytes;

    if (ws_size >= need_full) {
        // R19: 2 dispatches, no grid-wide sync, no global atomic RMW on data.
        uint32_t* bins = (uint32_t*)d_ws;
        int* partial = (int*)((char*)d_ws + bins_bytes);
        int* tickets = (int*)((char*)d_ws + bins_bytes + part_bytes);
        int* stg     = (int*)((char*)d_ws + bins_bytes + part_bytes + tick_bytes);

        dim3 gridA(16, NB);
        bin_kernel<<<gridA, 1024, 0, stream>>>(pc, tm, bins, partial, tickets);
        dim3 gridB(NB, 3, 4);   // b fastest -> same-batch blocks on one XCD
        splat_finalize_kernel<<<gridB, 1024, 0, stream>>>(bins, feat, partial,
                                                          tickets, stg, out);
    } else if (ws_size >= bins_bytes + part_bytes + tick_bytes) {
        // R16 path (verified): global-atomic flush + convert.
        uint32_t* bins = (uint32_t*)d_ws;
        int* partial = (int*)((char*)d_ws + bins_bytes);
        int* tickets = (int*)((char*)d_ws + bins_bytes + part_bytes);

        hipMemsetAsync(out, 0, (size_t)out_size * sizeof(float), stream);

        dim3 gridA(16, NB);
        bin_kernel<<<gridA, 1024, 0, stream>>>(pc, tm, bins, partial, tickets);
        dim3 gridB(NB, 3, 4);
        splat_ch_int_kernel<<<gridB, 1024, 0, stream>>>(bins, feat, partial, (int*)out);
        convert_kernel<<<(out_size + 1023) / 1024, 1024, 0, stream>>>(out);
    } else {
        int* mins = (int*)d_ws;  // 64 ints
        hipMemsetAsync(mins, 0x7F, 64 * sizeof(int), stream);
        dim3 grid(8, NB);
        kmin2_kernel<<<grid, 1024, 0, stream>>>(pc, tm, mins);
        dim3 gridB2(8, NB);
        splat_recompute_kernel<<<gridB2, 1024, 0, stream>>>(pc, feat, tm, mins, out);
    }
}

// Round 4
// 112.706 us; speedup vs baseline: 3.1272x; 1.5832x over previous
//
#include <hip/hip_runtime.h>
#include <stdint.h>

// Problem constants (from reference): D1=3, S=384, B=32, N=65536
#define NPTS 65536
#define NB   32
#define SS   384

// RN(1/3) in f32 = 0x3EAAAAAB
#define C3INV 0.333333343267440796f

// Fixed-point scale for histogram accumulation (R16): int LDS atomics emit a
// single native ds_add_u32. |bin sum| < ~65k -> scale 2^15 fits int32 with
// margin; quantization ~1.5e-5/add, worst bin ~6e-3 << 0.5 threshold.
#define FP_SCALE 32768.0f
#define FP_INV   (1.0f / 32768.0f)

// ---- LOCKED NUMERICS (R7, passed absmax<=0.0156) ----
__device__ __forceinline__ float fmul_strict(float a, float b) {
    float r;
    asm volatile("v_mul_f32 %0, %1, %2" : "=v"(r) : "v"(a), "v"(b));
    return r;
}
__device__ __forceinline__ float fadd_strict(float a, float b) {
    float r;
    asm volatile("v_add_f32 %0, %1, %2" : "=v"(r) : "v"(a), "v"(b));
    return r;
}

__device__ __forceinline__ void lattice_point(
    const float* __restrict__ t,
    float p0, float p1, float p2,
    int& gi0, int& gi1, int& rc0, int& rc1)
{
    float e0 = fadd_strict(fadd_strict(fmul_strict(t[0], p0), fmul_strict(t[1], p1)), fmul_strict(t[2], p2));
    float e1 = fadd_strict(fadd_strict(fmul_strict(t[3], p0), fmul_strict(t[4], p1)), fmul_strict(t[5], p2));
    float e2 = fadd_strict(fadd_strict(fmul_strict(t[6], p0), fmul_strict(t[7], p1)), fmul_strict(t[8], p2));

    float g0 = __fmul_rn(rintf(__fmul_rn(e0, C3INV)), 3.0f);
    float g1 = __fmul_rn(rintf(__fmul_rn(e1, C3INV)), 3.0f);
    float g2 = __fmul_rn(rintf(__fmul_rn(e2, C3INV)), 3.0f);

    float m0 = e0 - g0, m1 = e1 - g1, m2 = e2 - g2;
    int r0 = (int)(m1 > m0) + (int)(m2 > m0);
    int r1 = (int)(m0 >= m1) + (int)(m2 > m1);

    gi0 = (int)g0;
    gi1 = (int)g1;

    const int irs = (gi0 + gi1 + (int)g2) / 3;

    if (irs > 0) {
        if (r0 >= 3 - irs) { gi0 -= 3; r0 -= 3; }
        if (r1 >= 3 - irs) { gi1 -= 3; r1 -= 3; }
    } else if (irs < 0) {
        if (r0 < -irs) { gi0 += 3; r0 += 3; }
        if (r1 < -irs) { gi1 += 3; r1 += 3; }
    }
    r0 += irs;
    r1 += irs;

    if (r0 < 0) r0 += 3;
    if (r1 < 0) r1 += 3;
    rc0 = min(2, max(0, r0));
    rc1 = min(2, max(0, r1));
}

// ceil(a/3) for any sign (exact)
__device__ __forceinline__ int icl3(int a) {
    return (a >= 0) ? (a + 2) / 3 : -((-a) / 3);
}

// ============================ FAST PATH (R20) ============================
// 2 dispatches, ZERO cross-block communication (R18/R19 lesson: device-scope
// fences / coop sync cost ~60-100us on 8 non-coherent XCDs; the kernel
// boundary (~15-20us) is the only cheap global barrier).
//
// Kernel A: bin (unchanged, verified): float4 pc loads, uint4 bins store,
//           per-block mins -> partial.
// Kernel B: strip-owner splat: each block owns a 16x128 strip of one
//           (b,ch) histogram (8 KB LDS), scans ALL 64K points of (b,ch),
//           LDS-atomics only in-strip points, then converts + writes its
//           strip of `out` directly. Exactly-once ownership of every out
//           cell -> no memset, no staging, no reduction, no fences.
//           Redundant scan (x4 vs chunked) is L2-served: b is the fastest
//           grid dim -> all 24 blocks of batch b on one XCD; bins(256K)+
//           feat(768K) per b fit the 4MB XCD L2.

__global__ __launch_bounds__(1024) void bin_kernel(
    const float* __restrict__ pc, const float* __restrict__ tmg,
    uint32_t* __restrict__ bins, int* __restrict__ partial)
{
    const int bx  = blockIdx.x;   // 0..15
    const int b   = blockIdx.y;
    const int tid = threadIdx.x;

    __shared__ float t[9];
    if (tid < 9) t[tid] = tmg[b * 9 + tid];
    __syncthreads();

    const float* pcb = pc + (size_t)b * 3 * NPTS;
    const int v = bx * 1024 + tid;           // float4 group index

    const float4 P0 = ((const float4*)(pcb + 0 * NPTS))[v];
    const float4 P1 = ((const float4*)(pcb + 1 * NPTS))[v];
    const float4 P2 = ((const float4*)(pcb + 2 * NPTS))[v];

    int km0 = 0x7FFFFFFF, km1 = 0x7FFFFFFF;
    uint32_t pk[4];
    const float p0a[4] = {P0.x, P0.y, P0.z, P0.w};
    const float p1a[4] = {P1.x, P1.y, P1.z, P1.w};
    const float p2a[4] = {P2.x, P2.y, P2.z, P2.w};
#pragma unroll
    for (int i = 0; i < 4; ++i) {
        int gi0, gi1, rc0, rc1;
        lattice_point(t, p0a[i], p1a[i], p2a[i], gi0, gi1, rc0, rc1);
        pk[i] = (uint32_t)(((gi0 / 3 + 512) << 16) | (gi1 / 3 + 512));
        km0 = min(km0, gi0 - rc0);
        km1 = min(km1, gi1 - rc1);
    }
    ((uint4*)(bins + (size_t)b * NPTS))[v] = make_uint4(pk[0], pk[1], pk[2], pk[3]);

#pragma unroll
    for (int off = 32; off > 0; off >>= 1) {
        km0 = min(km0, __shfl_down(km0, off));
        km1 = min(km1, __shfl_down(km1, off));
    }
    __shared__ int s0[16], s1[16];
    if ((tid & 63) == 0) { s0[tid >> 6] = km0; s1[tid >> 6] = km1; }
    __syncthreads();
    if (tid == 0) {
        int m0 = s0[0], m1 = s1[0];
#pragma unroll
        for (int j = 1; j < 16; ++j) { m0 = min(m0, s0[j]); m1 = min(m1, s1[j]); }
        partial[(b * 16 + bx) * 2 + 0] = m0;
        partial[(b * 16 + bx) * 2 + 1] = m1;
    }
}

#define NSTRIP     8
#define STRIP_ROWS 16                       // 128 / NSTRIP
#define STRIP_INTS (STRIP_ROWS * 128)       // 2048 ints = 8 KB
#define STHREADS   512

__global__ __launch_bounds__(STHREADS) void splat_strip_kernel(
    const uint32_t* __restrict__ bins, const float* __restrict__ feat,
    const int* __restrict__ partial, float* __restrict__ out)
{
    const int b     = blockIdx.x;   // 0..31 (fastest -> XCD co-location)
    const int ch    = blockIdx.y;   // 0..2
    const int strip = blockIdx.z;   // 0..7
    const int tid   = threadIdx.x;  // 0..511

    __shared__ __align__(16) int ihist[STRIP_INTS];
    ((int4*)ihist)[tid] = make_int4(0, 0, 0, 0);   // 512 int4 = 8 KB exactly

    int off0 = 0x7FFFFFFF, off1 = 0x7FFFFFFF;
#pragma unroll
    for (int j = 0; j < 16; ++j) {
        off0 = min(off0, partial[(b * 16 + j) * 2 + 0]);
        off1 = min(off1, partial[(b * 16 + j) * 2 + 1]);
    }
    __syncthreads();

    // Global coords: y = (u>>16) - (512+icl3(off0)) in [0,?), x likewise.
    // Fold the strip base into K0: y_loc = y_glob - strip*16; the in-strip
    // test (unsigned)y_loc < 16 is exactly {strip*16 <= y_glob < strip*16+16},
    // and the 8 strips partition the original accepted set {0 <= y < 128}.
    const int K0 = 512 + icl3(off0) + strip * STRIP_ROWS;
    const int K1 = 512 + icl3(off1);

    const uint32_t* bb = bins + (size_t)b * NPTS;
    const float*    fb = feat + ((size_t)b * 3 + ch) * NPTS;

    // 65536 pts / 512 thr / 4 per vec = 32 iterations
#pragma unroll 4
    for (int i = 0; i < (NPTS / 4) / STHREADS; ++i) {
        const int v = i * STHREADS + tid;
        const uint4  U = ((const uint4 *)bb)[v];
        const float4 F = ((const float4*)fb)[v];

        const uint32_t ua[4] = {U.x, U.y, U.z, U.w};
        const float    fa[4] = {F.x, F.y, F.z, F.w};

#pragma unroll
        for (int k = 0; k < 4; ++k) {
            const int y = (int)(ua[k] >> 16) - K0;       // strip-local row
            const int x = (int)(ua[k] & 0xFFFFu) - K1;
            if ((unsigned)y < STRIP_ROWS && (unsigned)x < 128u) {
                const int q = (int)rintf(__fmul_rn(fa[k], FP_SCALE));
                atomicAdd(&ihist[(y << 7) + x], q);       // native ds_add_u32
            }
        }
    }
    __syncthreads();

    // Flush: this block exclusively owns cells [strip*2048, strip*2048+2048)
    // of (b, ch) -> convert + store directly (zeros included; no memset,
    // no second pass). out[((b*16384 + cell)*3) + ch], stride-12B dwords;
    // the 3 ch-blocks of b share lines and merge in the same XCD L2.
#pragma unroll
    for (int j = 0; j < STRIP_INTS / STHREADS; ++j) {     // 4
        const int idx = j * STHREADS + tid;
        const int v = ihist[idx];
        out[((size_t)(b << 14) + (size_t)strip * STRIP_INTS + idx) * 3 + ch] =
            __fmul_rn((float)v, FP_INV);
    }
}

// ========================= FALLBACK PATH ==========================
// Only if ws_size < bins+partial (never observed). 64 ints of ws.
#define FTILE_X 16
#define FHIST_F (128 * FTILE_X * 3)

__global__ __launch_bounds__(1024) void kmin2_kernel(
    const float* __restrict__ pc, const float* __restrict__ tmg,
    int* __restrict__ mins)
{
    const int b = blockIdx.y, bx = blockIdx.x, tid = threadIdx.x;
    __shared__ float t[9];
    if (tid < 9) t[tid] = tmg[b * 9 + tid];
    __syncthreads();

    const float* pcb = pc + (size_t)b * 3 * NPTS;
    int km0 = 0x7FFFFFFF, km1 = 0x7FFFFFFF;
    const int n0 = bx * 8192;
#pragma unroll
    for (int i = 0; i < 8; ++i) {
        const int n = n0 + i * 1024 + tid;
        int gi0, gi1, rc0, rc1;
        lattice_point(t, pcb[n], pcb[NPTS + n], pcb[2 * NPTS + n], gi0, gi1, rc0, rc1);
        km0 = min(km0, gi0 - rc0);
        km1 = min(km1, gi1 - rc1);
    }
#pragma unroll
    for (int off = 32; off > 0; off >>= 1) {
        km0 = min(km0, __shfl_down(km0, off));
        km1 = min(km1, __shfl_down(km1, off));
    }
    __shared__ int s0[16], s1[16];
    if ((tid & 63) == 0) { s0[tid >> 6] = km0; s1[tid >> 6] = km1; }
    __syncthreads();
    if (tid == 0) {
        int m0 = s0[0], m1 = s1[0];
#pragma unroll
        for (int j = 1; j < 16; ++j) { m0 = min(m0, s0[j]); m1 = min(m1, s1[j]); }
        atomicMin(&mins[b * 2 + 0], m0);
        atomicMin(&mins[b * 2 + 1], m1);
    }
}

__global__ __launch_bounds__(1024) void splat_recompute_kernel(
    const float* __restrict__ pc, const float* __restrict__ feat,
    const float* __restrict__ tmg, const int* __restrict__ mins,
    float* __restrict__ out)
{
    const int tile = blockIdx.x, b = blockIdx.y, tid = threadIdx.x;
    const int x0 = tile * FTILE_X;

    __shared__ float t[9];
    __shared__ float hist[FHIST_F];
    if (tid < 9) t[tid] = tmg[b * 9 + tid];
#pragma unroll
    for (int i = tid; i < FHIST_F; i += 1024) hist[i] = 0.0f;
    __syncthreads();

    const int off0 = mins[b * 2 + 0];
    const int off1 = mins[b * 2 + 1];
    const float* pcb = pc + (size_t)b * 3 * NPTS;
    const float* ftb = feat + (size_t)b * 3 * NPTS;

    for (int n = tid; n < NPTS; n += 1024) {
        int gi0, gi1, rc0, rc1;
        lattice_point(t, pcb[n], pcb[NPTS + n], pcb[2 * NPTS + n], gi0, gi1, rc0, rc1);
        const int c0 = gi0 - off0;
        const int c1 = gi1 - off1;
        if ((unsigned)c0 < SS && (unsigned)c1 < SS) {
            const int x = c1 / 3;
            if ((x >> 4) == tile) {
                const int y = c0 / 3;
                const int base = (y * FTILE_X + (x - x0)) * 3;
                atomicAdd(&hist[base + 0], ftb[0 * NPTS + n]);
                atomicAdd(&hist[base + 1], ftb[1 * NPTS + n]);
                atomicAdd(&hist[base + 2], ftb[2 * NPTS + n]);
            }
        }
    }
    __syncthreads();
#pragma unroll
    for (int idx = tid; idx < FHIST_F; idx += 1024) {
        const int y   = idx / (FTILE_X * 3);
        const int rem = idx - y * (FTILE_X * 3);
        out[(size_t)(b * 128 + y) * 384 + x0 * 3 + rem] = hist[idx];
    }
}

extern "C" void kernel_launch(void* const* d_in, const int* in_sizes, int n_in,
                              void* d_out, int out_size, void* d_ws, size_t ws_size,
                              hipStream_t stream) {
    const float* pc   = (const float*)d_in[0];  // (32,3,65536) f32
    const float* feat = (const float*)d_in[1];  // (32,3,65536) f32
    const float* tm   = (const float*)d_in[2];  // (32,3,3) f32
    float* out = (float*)d_out;                 // (32,128,128,3) f32

    const size_t bins_bytes = (size_t)NB * NPTS * sizeof(uint32_t);  // 8 MB
    const size_t part_bytes = 4096;                                  // 1024 ints
    const size_t need = bins_bytes + part_bytes;

    if (ws_size >= need) {
        // R20: 2 dispatches, no staging, no fences, no global atomics.
        uint32_t* bins = (uint32_t*)d_ws;
        int* partial = (int*)((char*)d_ws + bins_bytes);

        dim3 gridA(16, NB);
        bin_kernel<<<gridA, 1024, 0, stream>>>(pc, tm, bins, partial);
        dim3 gridB(NB, 3, NSTRIP);   // b fastest -> same-batch blocks on one XCD
        splat_strip_kernel<<<gridB, STHREADS, 0, stream>>>(bins, feat, partial, out);
    } else {
        int* mins = (int*)d_ws;  // 64 ints
        hipMemsetAsync(mins, 0x7F, 64 * sizeof(int), stream);
        dim3 grid(8, NB);
        kmin2_kernel<<<grid, 1024, 0, stream>>>(pc, tm, mins);
        dim3 gridB2(8, NB);
        splat_recompute_kernel<<<gridB2, 1024, 0, stream>>>(pc, feat, tm, mins, out);
    }
}

// Round 5
// 103.239 us; speedup vs baseline: 3.4140x; 1.0917x over previous
//
#include <hip/hip_runtime.h>
#include <stdint.h>

// Problem constants (from reference): D1=3, S=384, B=32, N=65536
#define NPTS 65536
#define NB   32
#define SS   384

// RN(1/3) in f32 = 0x3EAAAAAB
#define C3INV 0.333333343267440796f

// Fixed-point scale for histogram accumulation (R16): int LDS atomics emit a
// single native ds_add_u32. |bin sum| < ~65k -> scale 2^15 fits int32 with
// margin; quantization ~1.5e-5/add, worst bin ~6e-3 << 0.5 threshold.
#define FP_SCALE 32768.0f
#define FP_INV   (1.0f / 32768.0f)

// ---- LOCKED NUMERICS (R7, passed absmax<=0.0156) ----
__device__ __forceinline__ float fmul_strict(float a, float b) {
    float r;
    asm volatile("v_mul_f32 %0, %1, %2" : "=v"(r) : "v"(a), "v"(b));
    return r;
}
__device__ __forceinline__ float fadd_strict(float a, float b) {
    float r;
    asm volatile("v_add_f32 %0, %1, %2" : "=v"(r) : "v"(a), "v"(b));
    return r;
}

__device__ __forceinline__ void lattice_point(
    const float* __restrict__ t,
    float p0, float p1, float p2,
    int& gi0, int& gi1, int& rc0, int& rc1)
{
    float e0 = fadd_strict(fadd_strict(fmul_strict(t[0], p0), fmul_strict(t[1], p1)), fmul_strict(t[2], p2));
    float e1 = fadd_strict(fadd_strict(fmul_strict(t[3], p0), fmul_strict(t[4], p1)), fmul_strict(t[5], p2));
    float e2 = fadd_strict(fadd_strict(fmul_strict(t[6], p0), fmul_strict(t[7], p1)), fmul_strict(t[8], p2));

    float g0 = __fmul_rn(rintf(__fmul_rn(e0, C3INV)), 3.0f);
    float g1 = __fmul_rn(rintf(__fmul_rn(e1, C3INV)), 3.0f);
    float g2 = __fmul_rn(rintf(__fmul_rn(e2, C3INV)), 3.0f);

    float m0 = e0 - g0, m1 = e1 - g1, m2 = e2 - g2;
    int r0 = (int)(m1 > m0) + (int)(m2 > m0);
    int r1 = (int)(m0 >= m1) + (int)(m2 > m1);

    gi0 = (int)g0;
    gi1 = (int)g1;

    const int irs = (gi0 + gi1 + (int)g2) / 3;

    if (irs > 0) {
        if (r0 >= 3 - irs) { gi0 -= 3; r0 -= 3; }
        if (r1 >= 3 - irs) { gi1 -= 3; r1 -= 3; }
    } else if (irs < 0) {
        if (r0 < -irs) { gi0 += 3; r0 += 3; }
        if (r1 < -irs) { gi1 += 3; r1 += 3; }
    }
    r0 += irs;
    r1 += irs;

    if (r0 < 0) r0 += 3;
    if (r1 < 0) r1 += 3;
    rc0 = min(2, max(0, r0));
    rc1 = min(2, max(0, r1));
}

// ceil(a/3) for any sign (exact)
__device__ __forceinline__ int icl3(int a) {
    return (a >= 0) ? (a + 2) / 3 : -((-a) / 3);
}

// ============================ FAST PATH (R21) ============================
// Kernel-time budget is what matters: a ~60us fixed floor (harness 256MB
// ws re-poison fill @42us + launch overhead) sits under every run. R20's
// 8-strip splat paid 8x redundant per-point work (43us). R21 cuts the
// split to 2 halves (32KB LDS each): 192 blocks (1/CU), each block owns
// a 64x128 half-hist of one (b,ch), scans all 64K points once, and writes
// its out cells directly. Zero cross-block communication (R18/R19 lesson:
// device-scope fences/coop-sync cost 60-100us on 8 non-coherent XCDs).
//
// bin_kernel grid is b-fastest so batch b's bins are written from XCD b%8
// and re-read L2-locally by splat (splat linear%8 == b%8 too).

__global__ __launch_bounds__(1024) void bin_kernel(
    const float* __restrict__ pc, const float* __restrict__ tmg,
    uint32_t* __restrict__ bins, int* __restrict__ partial)
{
    const int b   = blockIdx.x;   // 0..31 (fastest -> XCD co-location w/ splat)
    const int bx  = blockIdx.y;   // 0..15
    const int tid = threadIdx.x;

    __shared__ float t[9];
    if (tid < 9) t[tid] = tmg[b * 9 + tid];
    __syncthreads();

    const float* pcb = pc + (size_t)b * 3 * NPTS;
    const int v = bx * 1024 + tid;           // float4 group index

    const float4 P0 = ((const float4*)(pcb + 0 * NPTS))[v];
    const float4 P1 = ((const float4*)(pcb + 1 * NPTS))[v];
    const float4 P2 = ((const float4*)(pcb + 2 * NPTS))[v];

    int km0 = 0x7FFFFFFF, km1 = 0x7FFFFFFF;
    uint32_t pk[4];
    const float p0a[4] = {P0.x, P0.y, P0.z, P0.w};
    const float p1a[4] = {P1.x, P1.y, P1.z, P1.w};
    const float p2a[4] = {P2.x, P2.y, P2.z, P2.w};
#pragma unroll
    for (int i = 0; i < 4; ++i) {
        int gi0, gi1, rc0, rc1;
        lattice_point(t, p0a[i], p1a[i], p2a[i], gi0, gi1, rc0, rc1);
        pk[i] = (uint32_t)(((gi0 / 3 + 512) << 16) | (gi1 / 3 + 512));
        km0 = min(km0, gi0 - rc0);
        km1 = min(km1, gi1 - rc1);
    }
    ((uint4*)(bins + (size_t)b * NPTS))[v] = make_uint4(pk[0], pk[1], pk[2], pk[3]);

#pragma unroll
    for (int off = 32; off > 0; off >>= 1) {
        km0 = min(km0, __shfl_down(km0, off));
        km1 = min(km1, __shfl_down(km1, off));
    }
    __shared__ int s0[16], s1[16];
    if ((tid & 63) == 0) { s0[tid >> 6] = km0; s1[tid >> 6] = km1; }
    __syncthreads();
    if (tid == 0) {
        int m0 = s0[0], m1 = s1[0];
#pragma unroll
        for (int j = 1; j < 16; ++j) { m0 = min(m0, s0[j]); m1 = min(m1, s1[j]); }
        partial[(b * 16 + bx) * 2 + 0] = m0;
        partial[(b * 16 + bx) * 2 + 1] = m1;
    }
}

#define NHALF      2
#define HALF_ROWS  64                        // 128 / NHALF
#define HALF_INTS  (HALF_ROWS * 128)         // 8192 ints = 32 KB
#define HTHREADS   1024

__global__ __launch_bounds__(HTHREADS) void splat_half_kernel(
    const uint32_t* __restrict__ bins, const float* __restrict__ feat,
    const int* __restrict__ partial, float* __restrict__ out)
{
    const int b    = blockIdx.x;   // 0..31 (fastest -> XCD co-location)
    const int ch   = blockIdx.y;   // 0..2
    const int half = blockIdx.z;   // 0..1
    const int tid  = threadIdx.x;  // 0..1023

    __shared__ __align__(16) int ihist[HALF_INTS];
#pragma unroll
    for (int j = 0; j < HALF_INTS / 4 / HTHREADS; ++j)     // 2
        ((int4*)ihist)[j * HTHREADS + tid] = make_int4(0, 0, 0, 0);

    int off0 = 0x7FFFFFFF, off1 = 0x7FFFFFFF;
#pragma unroll
    for (int j = 0; j < 16; ++j) {
        off0 = min(off0, partial[(b * 16 + j) * 2 + 0]);
        off1 = min(off1, partial[(b * 16 + j) * 2 + 1]);
    }
    __syncthreads();

    // Fold the half base into K0: y_loc = y_glob - half*64; the in-half test
    // (unsigned)y_loc < 64 partitions the verified accepted set {0<=y<128}.
    const int K0 = 512 + icl3(off0) + half * HALF_ROWS;
    const int K1 = 512 + icl3(off1);

    const uint32_t* bb = bins + (size_t)b * NPTS;
    const float*    fb = feat + ((size_t)b * 3 + ch) * NPTS;

    // 65536 pts / 1024 thr / 4 per vec = 16 iterations
#pragma unroll 4
    for (int i = 0; i < (NPTS / 4) / HTHREADS; ++i) {
        const int v = i * HTHREADS + tid;
        const uint4  U = ((const uint4 *)bb)[v];
        const float4 F = ((const float4*)fb)[v];

        const uint32_t ua[4] = {U.x, U.y, U.z, U.w};
        const float    fa[4] = {F.x, F.y, F.z, F.w};

#pragma unroll
        for (int k = 0; k < 4; ++k) {
            const int y = (int)(ua[k] >> 16) - K0;       // half-local row
            const int x = (int)(ua[k] & 0xFFFFu) - K1;
            if ((unsigned)y < HALF_ROWS && (unsigned)x < 128u) {
                const int q = (int)rintf(__fmul_rn(fa[k], FP_SCALE));
                atomicAdd(&ihist[(y << 7) + x], q);       // native ds_add_u32
            }
        }
    }
    __syncthreads();

    // Flush: exclusive ownership of cells [half*8192, half*8192+8192) of
    // (b,ch) -> convert + store directly (zeros included; no memset, no
    // second pass). out[((b*16384 + cell)*3) + ch]; the 3 ch-blocks of b
    // merge lines in their shared XCD L2.
#pragma unroll
    for (int j = 0; j < HALF_INTS / HTHREADS; ++j) {      // 8
        const int idx = j * HTHREADS + tid;
        const int v = ihist[idx];
        out[((size_t)(b << 14) + (size_t)half * HALF_INTS + idx) * 3 + ch] =
            __fmul_rn((float)v, FP_INV);
    }
}

// ========================= FALLBACK PATH ==========================
// Only if ws_size < bins+partial (never observed). 64 ints of ws.
#define FTILE_X 16
#define FHIST_F (128 * FTILE_X * 3)

__global__ __launch_bounds__(1024) void kmin2_kernel(
    const float* __restrict__ pc, const float* __restrict__ tmg,
    int* __restrict__ mins)
{
    const int b = blockIdx.y, bx = blockIdx.x, tid = threadIdx.x;
    __shared__ float t[9];
    if (tid < 9) t[tid] = tmg[b * 9 + tid];
    __syncthreads();

    const float* pcb = pc + (size_t)b * 3 * NPTS;
    int km0 = 0x7FFFFFFF, km1 = 0x7FFFFFFF;
    const int n0 = bx * 8192;
#pragma unroll
    for (int i = 0; i < 8; ++i) {
        const int n = n0 + i * 1024 + tid;
        int gi0, gi1, rc0, rc1;
        lattice_point(t, pcb[n], pcb[NPTS + n], pcb[2 * NPTS + n], gi0, gi1, rc0, rc1);
        km0 = min(km0, gi0 - rc0);
        km1 = min(km1, gi1 - rc1);
    }
#pragma unroll
    for (int off = 32; off > 0; off >>= 1) {
        km0 = min(km0, __shfl_down(km0, off));
        km1 = min(km1, __shfl_down(km1, off));
    }
    __shared__ int s0[16], s1[16];
    if ((tid & 63) == 0) { s0[tid >> 6] = km0; s1[tid >> 6] = km1; }
    __syncthreads();
    if (tid == 0) {
        int m0 = s0[0], m1 = s1[0];
#pragma unroll
        for (int j = 1; j < 16; ++j) { m0 = min(m0, s0[j]); m1 = min(m1, s1[j]); }
        atomicMin(&mins[b * 2 + 0], m0);
        atomicMin(&mins[b * 2 + 1], m1);
    }
}

__global__ __launch_bounds__(1024) void splat_recompute_kernel(
    const float* __restrict__ pc, const float* __restrict__ feat,
    const float* __restrict__ tmg, const int* __restrict__ mins,
    float* __restrict__ out)
{
    const int tile = blockIdx.x, b = blockIdx.y, tid = threadIdx.x;
    const int x0 = tile * FTILE_X;

    __shared__ float t[9];
    __shared__ float hist[FHIST_F];
    if (tid < 9) t[tid] = tmg[b * 9 + tid];
#pragma unroll
    for (int i = tid; i < FHIST_F; i += 1024) hist[i] = 0.0f;
    __syncthreads();

    const int off0 = mins[b * 2 + 0];
    const int off1 = mins[b * 2 + 1];
    const float* pcb = pc + (size_t)b * 3 * NPTS;
    const float* ftb = feat + (size_t)b * 3 * NPTS;

    for (int n = tid; n < NPTS; n += 1024) {
        int gi0, gi1, rc0, rc1;
        lattice_point(t, pcb[n], pcb[NPTS + n], pcb[2 * NPTS + n], gi0, gi1, rc0, rc1);
        const int c0 = gi0 - off0;
        const int c1 = gi1 - off1;
        if ((unsigned)c0 < SS && (unsigned)c1 < SS) {
            const int x = c1 / 3;
            if ((x >> 4) == tile) {
                const int y = c0 / 3;
                const int base = (y * FTILE_X + (x - x0)) * 3;
                atomicAdd(&hist[base + 0], ftb[0 * NPTS + n]);
                atomicAdd(&hist[base + 1], ftb[1 * NPTS + n]);
                atomicAdd(&hist[base + 2], ftb[2 * NPTS + n]);
            }
        }
    }
    __syncthreads();
#pragma unroll
    for (int idx = tid; idx < FHIST_F; idx += 1024) {
        const int y   = idx / (FTILE_X * 3);
        const int rem = idx - y * (FTILE_X * 3);
        out[(size_t)(b * 128 + y) * 384 + x0 * 3 + rem] = hist[idx];
    }
}

extern "C" void kernel_launch(void* const* d_in, const int* in_sizes, int n_in,
                              void* d_out, int out_size, void* d_ws, size_t ws_size,
                              hipStream_t stream) {
    const float* pc   = (const float*)d_in[0];  // (32,3,65536) f32
    const float* feat = (const float*)d_in[1];  // (32,3,65536) f32
    const float* tm   = (const float*)d_in[2];  // (32,3,3) f32
    float* out = (float*)d_out;                 // (32,128,128,3) f32

    const size_t bins_bytes = (size_t)NB * NPTS * sizeof(uint32_t);  // 8 MB
    const size_t part_bytes = 4096;                                  // 1024 ints
    const size_t need = bins_bytes + part_bytes;

    if (ws_size >= need) {
        // R21: 2 dispatches, no staging, no fences, no global atomics.
        uint32_t* bins = (uint32_t*)d_ws;
        int* partial = (int*)((char*)d_ws + bins_bytes);

        dim3 gridA(NB, 16);          // b fastest -> bins written on XCD b%8
        bin_kernel<<<gridA, 1024, 0, stream>>>(pc, tm, bins, partial);
        dim3 gridB(NB, 3, NHALF);    // 192 blocks, 1/CU, b fastest
        splat_half_kernel<<<gridB, HTHREADS, 0, stream>>>(bins, feat, partial, out);
    } else {
        int* mins = (int*)d_ws;  // 64 ints
        hipMemsetAsync(mins, 0x7F, 64 * sizeof(int), stream);
        dim3 grid(8, NB);
        kmin2_kernel<<<grid, 1024, 0, stream>>>(pc, tm, mins);
        dim3 gridB2(8, NB);
        splat_recompute_kernel<<<gridB2, 1024, 0, stream>>>(pc, feat, tm, mins, out);
    }
}